// Round 5
// baseline (910.195 us; speedup 1.0000x reference)
//
#include <hip/hip_runtime.h>
#include <math.h>

#define B_ 4
#define T_ 16
#define H_ 64
#define W_ 64
#define CIN 32
#define CO 64
#define NG 256   // 4*CO gate channels
#define PXS 40   // padded per-pixel stride in shorts (80 B): 16B-aligned, spreads LDS banks

typedef __attribute__((ext_vector_type(8))) short bf16x8;
typedef __attribute__((ext_vector_type(4))) float f32x4;

__device__ __forceinline__ float hsig(float z) {
    return fminf(1.f, fmaxf(0.f, 0.2f * z + 0.5f));
}

// fast tanh: v_exp_f32 + v_rcp_f32. Saturation exact at +/-inf.
__device__ __forceinline__ float ftanh(float x) {
    float e = __builtin_amdgcn_exp2f(x * 2.8853900817779268f);  // 2*log2(e)
    return 1.f - 2.f * __builtin_amdgcn_rcpf(e + 1.f);
}

__device__ __forceinline__ unsigned short f2bf(float f) {
    union { float f; unsigned u; } v; v.f = f;
    unsigned r = v.u + 0x7FFFu + ((v.u >> 16) & 1u);   // RTNE
    return (unsigned short)(r >> 16);
}

// Transpose+convert weights once per launch:
//   wkT[kpos][n=256][k=32]        from wk (3,3,32,256)
//   wrT[kpos][q=2][n=256][k=32]   from wr (3,3,64,256), q = cin chunk of 32
__global__ void transform_weights(const float* __restrict__ wk,
                                  const float* __restrict__ wr,
                                  unsigned short* __restrict__ wkT,
                                  unsigned short* __restrict__ wrT)
{
    int i = blockIdx.x * 256 + threadIdx.x;
    if (i < 9 * 256 * 32) {
        int k = i & 31, n = (i >> 5) & 255, kpos = i >> 13;
        wkT[i] = f2bf(wk[(kpos * 32 + k) * 256 + n]);
    }
    if (i < 9 * 2 * 256 * 32) {
        int k = i & 31, n = (i >> 5) & 255, q = (i >> 13) & 1, kpos = i >> 14;
        wrT[i] = f2bf(wr[(kpos * 64 + q * 32 + k) * 256 + n]);
    }
}

// One timestep. Block = 64 px (4 rows x 16 cols), 512 threads = 8 waves.
// Balanced k-split over the 27 (kpos,q) chunks of the fused conv:
//   x-waves (4-7): x-conv (9 chunks) + h-conv q1 kpos 0-4 (5)  = 14 chunks
//   h-waves (0-3): h-conv q0 (9 chunks) + q1 kpos 5-8 (4)      = 13 chunks
// Depth-4 register pipeline on weight fragments (prefetch chunk i+3 at chunk i)
// to cover L2/L3 fetch latency. Symmetric LDS exchange: x-waves publish
// partials for row-tiles 0-1 and run the epilogue for tiles 2-3; h-waves the
// reverse. Both roles stay busy end-to-end (2 waves/SIMD throughout).
template<bool FIRST>
__global__ __launch_bounds__(512, 2)
void convlstm_step(const float* __restrict__ x,
                   const unsigned short* __restrict__ wkT,
                   const unsigned short* __restrict__ wrT,
                   const float* __restrict__ bias,
                   const float* __restrict__ gamma,
                   const float* __restrict__ beta,
                   const float* __restrict__ mean,
                   const float* __restrict__ var,
                   const unsigned short* __restrict__ hin,   // bf16 NHWC
                   unsigned short* __restrict__ hout,        // bf16 NHWC
                   float* __restrict__ cbuf,
                   float* __restrict__ out,
                   int t)
{
    __shared__ __align__(16) unsigned short sx[6 * 18 * PXS];        //  8.6 KB
    __shared__ __align__(16) unsigned short sh[2][6 * 18 * PXS];     // 17.3 KB
    // partial exchange: [slice4][gate4][row4][ch16][px 16 + 4 pad] fp32 = 80 KB
    __shared__ __align__(16) float axx[4 * 4 * 4 * 16 * 20];

    const int tid = threadIdx.x;
    const int wv = tid >> 6, lane = tid & 63;
    const int ln = lane & 15, kg = lane >> 4;
    const bool hwave = (wv < 4);
    const int sl = wv & 3;                 // n-slice: ch = sl*16 + ln

    const int bi = blockIdx.x;
    const int b = bi >> 6, tile = bi & 63;
    const int oy = (tile >> 2) * 4;        // 16 row-tiles
    const int ox = (tile & 3) * 16;        // 4 col-tiles

    // ---- parallel staging: x-waves stage sx, h-waves stage sh ----
    if (!hwave) {
        // x halo (fp32 -> bf16): 108 positions x 4 chunks of 8 cin = 432 elems
#pragma unroll
        for (int i = 0; i < 2; ++i) {
            int e = (tid - 256) + i * 256;
            if (e < 432) {
                int c8 = e & 3, p = e >> 2;
                int row = p / 18, col = p - row * 18;
                int gy = oy - 1 + row, gx = ox - 1 + col;
                float4 v0 = make_float4(0.f, 0.f, 0.f, 0.f), v1 = v0;
                if ((unsigned)gy < (unsigned)H_ && (unsigned)gx < (unsigned)W_) {
                    const float* p32 = &x[((((size_t)b * T_ + t) * H_ + gy) * W_ + gx) * CIN + c8 * 8];
                    v0 = *(const float4*)p32; v1 = *(const float4*)(p32 + 4);
                }
                unsigned short* d = &sx[(row * 18 + col) * PXS + c8 * 8];
                d[0] = f2bf(v0.x); d[1] = f2bf(v0.y); d[2] = f2bf(v0.z); d[3] = f2bf(v0.w);
                d[4] = f2bf(v1.x); d[5] = f2bf(v1.y); d[6] = f2bf(v1.z); d[7] = f2bf(v1.w);
            }
        }
    } else if (!FIRST) {
        // h halo (bf16 copy): 108 positions x 8 octs of 8 ch = 864 elems
#pragma unroll
        for (int i = 0; i < 4; ++i) {
            int e = tid + i * 256;
            if (e < 864) {
                int o = e & 7, p = e >> 3;
                int row = p / 18, col = p - row * 18;
                int gy = oy - 1 + row, gx = ox - 1 + col;
                uint4 v = make_uint4(0u, 0u, 0u, 0u);
                if ((unsigned)gy < (unsigned)H_ && (unsigned)gx < (unsigned)W_)
                    v = *(const uint4*)&hin[(((size_t)b * H_ + gy) * W_ + gx) * CO + o * 8];
                int q = o >> 2, s4 = o & 3;
                *(uint4*)&sh[q][(row * 18 + col) * PXS + s4 * 8] = v;
            }
        }
    }

    const int nbase = sl * 16 + ln;
    const int ch = nbase;
    const unsigned short* wkp = wkT + (size_t)nbase * 32 + kg * 8;
    const unsigned short* wrp = wrT + (size_t)nbase * 32 + kg * 8;

    // ---- hoisted epilogue inputs (both roles, their own row-pair) ----
    // h-waves own rows 0-1, x-waves own rows 2-3.
    const int rbase = hwave ? 0 : 2;
    const float bi0 = bias[ch], bi1 = bias[64 + ch], bi2 = bias[128 + ch], bi3 = bias[192 + ch];
    const float inv = gamma[ch] * rsqrtf(var[ch] + 1e-3f);
    const float shift = beta[ch] - mean[ch] * inv;
    float cprev[2][4];
    if (!FIRST) {
#pragma unroll
        for (int rr = 0; rr < 2; ++rr)
#pragma unroll
            for (int reg = 0; reg < 4; ++reg) {
                size_t pix = ((size_t)b * H_ + oy + rbase + rr) * W_ + (ox + kg * 4 + reg);
                cprev[rr][reg] = cbuf[pix * CO + ch];
            }
    } else {
#pragma unroll
        for (int rr = 0; rr < 2; ++rr)
#pragma unroll
            for (int reg = 0; reg < 4; ++reg) cprev[rr][reg] = 0.f;
    }

    __syncthreads();

    f32x4 acc[4][4];   // [gate][row-tile]
#pragma unroll
    for (int g = 0; g < 4; ++g)
#pragma unroll
        for (int r = 0; r < 4; ++r) acc[g][r] = (f32x4){0.f, 0.f, 0.f, 0.f};

// weight-fragment load for chunk i (compile-time i under full unroll)
#define LOADW_X(dst, i) {                                                        \
    const unsigned short* wp_ = (i < 9) ? (wkp + (size_t)(i) * 8192)             \
                                        : (wrp + (size_t)(((i) - 9) * 2 + 1) * 8192); \
    dst[0] = *(const bf16x8*)(wp_);                                              \
    dst[1] = *(const bf16x8*)(wp_ + 2048);                                       \
    dst[2] = *(const bf16x8*)(wp_ + 4096);                                       \
    dst[3] = *(const bf16x8*)(wp_ + 6144); }
#define LOADW_H(dst, i) {                                                        \
    const unsigned short* wp_ = (i < 9) ? (wrp + (size_t)((i) * 2) * 8192)       \
                                        : (wrp + (size_t)(((i) - 4) * 2 + 1) * 8192); \
    dst[0] = *(const bf16x8*)(wp_);                                              \
    dst[1] = *(const bf16x8*)(wp_ + 2048);                                       \
    dst[2] = *(const bf16x8*)(wp_ + 4096);                                       \
    dst[3] = *(const bf16x8*)(wp_ + 6144); }

    if (!hwave) {
        // x-wave: chunks 0-8 = x-conv kpos 0-8 (src sx); 9-13 = h-conv q1 kpos 0-4 (src sh[1])
        constexpr int NC = FIRST ? 9 : 14;
        bf16x8 pipe[4][4];
#pragma unroll
        for (int i = 0; i < 3; ++i) { if (i < NC) LOADW_X(pipe[i], i); }
#pragma unroll
        for (int i = 0; i < NC; ++i) {
            if (i + 3 < NC) LOADW_X(pipe[(i + 3) & 3], (i + 3));
            const int kq = (i < 9) ? i : i - 9;
            const int ky = kq / 3, kx = kq - ky * 3;
            const unsigned short* sb = (i < 9) ? sx : sh[1];
            bf16x8 a[4];
#pragma unroll
            for (int r = 0; r < 4; ++r)
                a[r] = *(const bf16x8*)&sb[((r + ky) * 18 + ln + kx) * PXS + kg * 8];
            __builtin_amdgcn_s_setprio(1);
#pragma unroll
            for (int g = 0; g < 4; ++g)
#pragma unroll
                for (int r = 0; r < 4; ++r)
                    acc[g][r] = __builtin_amdgcn_mfma_f32_16x16x32_bf16(a[r], pipe[i & 3][g], acc[g][r], 0, 0, 0);
            __builtin_amdgcn_s_setprio(0);
        }
    } else if (!FIRST) {
        // h-wave: chunks 0-8 = h-conv q0 kpos 0-8 (src sh[0]); 9-12 = q1 kpos 5-8 (src sh[1])
        constexpr int NC = 13;
        bf16x8 pipe[4][4];
#pragma unroll
        for (int i = 0; i < 3; ++i) { LOADW_H(pipe[i], i); }
#pragma unroll
        for (int i = 0; i < NC; ++i) {
            if (i + 3 < NC) LOADW_H(pipe[(i + 3) & 3], (i + 3));
            const int kq = (i < 9) ? i : i - 4;
            const int ky = kq / 3, kx = kq - ky * 3;
            const unsigned short* sb = (i < 9) ? sh[0] : sh[1];
            bf16x8 a[4];
#pragma unroll
            for (int r = 0; r < 4; ++r)
                a[r] = *(const bf16x8*)&sb[((r + ky) * 18 + ln + kx) * PXS + kg * 8];
            __builtin_amdgcn_s_setprio(1);
#pragma unroll
            for (int g = 0; g < 4; ++g)
#pragma unroll
                for (int r = 0; r < 4; ++r)
                    acc[g][r] = __builtin_amdgcn_mfma_f32_16x16x32_bf16(a[r], pipe[i & 3][g], acc[g][r], 0, 0, 0);
            __builtin_amdgcn_s_setprio(0);
        }
    }

    // ---- symmetric exchange: each role publishes the OTHER role's rows ----
    // x-waves publish partials for rows 0-1 (h-waves' epilogue half);
    // h-waves publish partials for rows 2-3 (x-waves' epilogue half).
    {
        const int pb = hwave ? 2 : 0;
#pragma unroll
        for (int g = 0; g < 4; ++g)
#pragma unroll
            for (int rr = 0; rr < 2; ++rr)
                *(f32x4*)&axx[((((sl * 4 + g) * 4 + (pb + rr)) * 16) + ln) * 20 + kg * 4] = acc[g][pb + rr];
    }
    __syncthreads();

    // ---- merge + epilogue for own rows (rbase..rbase+1), both roles ----
#pragma unroll
    for (int rr = 0; rr < 2; ++rr) {
        const int r = rbase + rr;
        const int gy = oy + r;
        f32x4 av[4];
#pragma unroll
        for (int g = 0; g < 4; ++g) {
            f32x4 v = *(const f32x4*)&axx[((((sl * 4 + g) * 4 + r) * 16) + ln) * 20 + kg * 4];
            av[g] = acc[g][r] + v;
        }
#pragma unroll
        for (int reg = 0; reg < 4; ++reg) {
            const int gx = ox + kg * 4 + reg;
            size_t pix = ((size_t)b * H_ + gy) * W_ + gx;
            float ig = hsig(av[0][reg] + bi0);
            float fg = hsig(av[1][reg] + bi1);
            float cg = ftanh(av[2][reg] + bi2);
            float og = hsig(av[3][reg] + bi3);
            float cv = fg * cprev[rr][reg] + ig * cg;
            float hv = og * ftanh(cv);
            __builtin_nontemporal_store(cv, &cbuf[pix * CO + ch]);
            hout[pix * CO + ch] = f2bf(hv);
            __builtin_nontemporal_store(hv * inv + shift,
                &out[((((size_t)b * T_ + t) * H_ + gy) * W_ + gx) * CO + ch]);
        }
    }
}

extern "C" void kernel_launch(void* const* d_in, const int* in_sizes, int n_in,
                              void* d_out, int out_size, void* d_ws, size_t ws_size,
                              hipStream_t stream)
{
    (void)in_sizes; (void)n_in; (void)out_size; (void)ws_size;
    const float* x     = (const float*)d_in[0];
    const float* wk    = (const float*)d_in[1];
    const float* wr    = (const float*)d_in[2];
    const float* bias  = (const float*)d_in[3];
    const float* gamma = (const float*)d_in[4];
    const float* beta  = (const float*)d_in[5];
    const float* mean  = (const float*)d_in[6];
    const float* var   = (const float*)d_in[7];
    float* out = (float*)d_out;

    const size_t plane = (size_t)B_ * H_ * W_ * CO;           // 1,048,576 elems
    unsigned short* h0 = (unsigned short*)d_ws;               // bf16, 2 MB
    unsigned short* h1 = h0 + plane;                          // bf16, 2 MB
    float* cb = (float*)(h1 + plane);                         // fp32, 4 MB
    unsigned short* wkT = (unsigned short*)(cb + plane);      // 147 KB
    unsigned short* wrT = wkT + 9 * 256 * 32;                 // 295 KB

    transform_weights<<<576, 256, 0, stream>>>(wk, wr, wkT, wrT);

    for (int t = 0; t < T_; ++t) {
        const unsigned short* hin = (t & 1) ? h0 : h1;  // garbage at t==0 (unused)
        unsigned short* houtp     = (t & 1) ? h1 : h0;
        if (t == 0)
            convlstm_step<true><<<256, 512, 0, stream>>>(x, wkT, wrT, bias, gamma, beta, mean, var,
                                                         hin, houtp, cb, out, t);
        else
            convlstm_step<false><<<256, 512, 0, stream>>>(x, wkT, wrT, bias, gamma, beta, mean, var,
                                                          hin, houtp, cb, out, t);
    }
}

// Round 6
// 686.223 us; speedup vs baseline: 1.3264x; 1.3264x over previous
//
#include <hip/hip_runtime.h>
#include <math.h>

#define B_ 4
#define T_ 16
#define H_ 64
#define W_ 64
#define CIN 32
#define CO 64
#define NG 256   // 4*CO gate channels
#define PXS 40   // padded per-pixel stride in shorts (80 B): 16B-aligned, spreads LDS banks

typedef __attribute__((ext_vector_type(8))) short bf16x8;
typedef __attribute__((ext_vector_type(4))) float f32x4;

__device__ __forceinline__ float hsig(float z) {
    return fminf(1.f, fmaxf(0.f, 0.2f * z + 0.5f));
}

// fast tanh: v_exp_f32 + v_rcp_f32. Saturation exact at +/-inf.
__device__ __forceinline__ float ftanh(float x) {
    float e = __builtin_amdgcn_exp2f(x * 2.8853900817779268f);  // 2*log2(e)
    return 1.f - 2.f * __builtin_amdgcn_rcpf(e + 1.f);
}

__device__ __forceinline__ unsigned short f2bf(float f) {
    union { float f; unsigned u; } v; v.f = f;
    unsigned r = v.u + 0x7FFFu + ((v.u >> 16) & 1u);   // RTNE
    return (unsigned short)(r >> 16);
}

// Transpose+convert weights once per launch:
//   wkT[kpos][n=256][k=32]        from wk (3,3,32,256)
//   wrT[kpos][q=2][n=256][k=32]   from wr (3,3,64,256), q = cin chunk of 32
__global__ void transform_weights(const float* __restrict__ wk,
                                  const float* __restrict__ wr,
                                  unsigned short* __restrict__ wkT,
                                  unsigned short* __restrict__ wrT)
{
    int i = blockIdx.x * 256 + threadIdx.x;
    if (i < 9 * 256 * 32) {
        int k = i & 31, n = (i >> 5) & 255, kpos = i >> 13;
        wkT[i] = f2bf(wk[(kpos * 32 + k) * 256 + n]);
    }
    if (i < 9 * 2 * 256 * 32) {
        int k = i & 31, n = (i >> 5) & 255, q = (i >> 13) & 1, kpos = i >> 14;
        wrT[i] = f2bf(wr[(kpos * 64 + q * 32 + k) * 256 + n]);
    }
}

// One timestep. Block = 64 px (4 rows x 16 cols), 512 threads = 8 waves.
// Balanced k-split over the 27 (kpos,q) chunks of the fused conv:
//   x-waves (4-7): x-conv (9 chunks) + h-conv q1 kpos 0-4 (5)  = 14 chunks
//   h-waves (0-3): h-conv q0 (9 chunks) + q1 kpos 5-8 (4)      = 13 chunks
// Depth-4 weight-fragment pipeline with PREPROCESSOR-EXPANDED literal chunk
// indices (every subscript compile-time constant -> stays in VGPRs; the
// R4 IV-indexed version was demoted to scratch: VGPR=96, WRITE 175 MB/step).
// Symmetric exchange: x-waves publish rows 0-1 / epilogue rows 2-3; h-waves
// the reverse. 2 role-split waves/SIMD end-to-end.
template<bool FIRST>
__global__ __launch_bounds__(512, 2)
void convlstm_step(const float* __restrict__ x,
                   const unsigned short* __restrict__ wkT,
                   const unsigned short* __restrict__ wrT,
                   const float* __restrict__ bias,
                   const float* __restrict__ gamma,
                   const float* __restrict__ beta,
                   const float* __restrict__ mean,
                   const float* __restrict__ var,
                   const unsigned short* __restrict__ hin,   // bf16 NHWC
                   unsigned short* __restrict__ hout,        // bf16 NHWC
                   float* __restrict__ cbuf,
                   float* __restrict__ out,
                   int t)
{
    __shared__ __align__(16) unsigned short sx[6 * 18 * PXS];        //  8.6 KB
    __shared__ __align__(16) unsigned short shm[2][6 * 18 * PXS];    // 17.3 KB
    // partial exchange: [slice4][gate4][row4][ch16][px 16 + 4 pad] fp32 = 80 KB
    __shared__ __align__(16) float axx[4 * 4 * 4 * 16 * 20];

    const int tid = threadIdx.x;
    const int wv = tid >> 6, lane = tid & 63;
    const int ln = lane & 15, kg = lane >> 4;
    const bool hwave = (wv < 4);
    const int sl = wv & 3;                 // n-slice: ch = sl*16 + ln

    const int bi = blockIdx.x;
    const int b = bi >> 6, tile = bi & 63;
    const int oy = (tile >> 2) * 4;        // 16 row-tiles
    const int ox = (tile & 3) * 16;        // 4 col-tiles

    unsigned short* sh0 = shm[0];
    unsigned short* sh1 = shm[1];

    // ---- parallel staging: x-waves stage sx, h-waves stage sh ----
    if (!hwave) {
        // x halo (fp32 -> bf16): 108 positions x 4 chunks of 8 cin = 432 elems
#pragma unroll
        for (int i = 0; i < 2; ++i) {
            int e = (tid - 256) + i * 256;
            if (e < 432) {
                int c8 = e & 3, p = e >> 2;
                int row = p / 18, col = p - row * 18;
                int gy = oy - 1 + row, gx = ox - 1 + col;
                float4 v0 = make_float4(0.f, 0.f, 0.f, 0.f), v1 = v0;
                if ((unsigned)gy < (unsigned)H_ && (unsigned)gx < (unsigned)W_) {
                    const float* p32 = &x[((((size_t)b * T_ + t) * H_ + gy) * W_ + gx) * CIN + c8 * 8];
                    v0 = *(const float4*)p32; v1 = *(const float4*)(p32 + 4);
                }
                unsigned short* d = &sx[(row * 18 + col) * PXS + c8 * 8];
                d[0] = f2bf(v0.x); d[1] = f2bf(v0.y); d[2] = f2bf(v0.z); d[3] = f2bf(v0.w);
                d[4] = f2bf(v1.x); d[5] = f2bf(v1.y); d[6] = f2bf(v1.z); d[7] = f2bf(v1.w);
            }
        }
    } else if (!FIRST) {
        // h halo (bf16 copy): 108 positions x 8 octs of 8 ch = 864 elems
#pragma unroll
        for (int i = 0; i < 4; ++i) {
            int e = tid + i * 256;
            if (e < 864) {
                int o = e & 7, p = e >> 3;
                int row = p / 18, col = p - row * 18;
                int gy = oy - 1 + row, gx = ox - 1 + col;
                uint4 v = make_uint4(0u, 0u, 0u, 0u);
                if ((unsigned)gy < (unsigned)H_ && (unsigned)gx < (unsigned)W_)
                    v = *(const uint4*)&hin[(((size_t)b * H_ + gy) * W_ + gx) * CO + o * 8];
                int q = o >> 2, s4 = o & 3;
                *(uint4*)&shm[q][(row * 18 + col) * PXS + s4 * 8] = v;
            }
        }
    }

    const int nbase = sl * 16 + ln;
    const int ch = nbase;
    const unsigned short* wkp = wkT + (size_t)nbase * 32 + kg * 8;
    const unsigned short* wrp = wrT + (size_t)nbase * 32 + kg * 8;

    // ---- hoisted epilogue inputs (both roles, their own row-pair) ----
    // h-waves own rows 0-1, x-waves own rows 2-3.
    const int rbase = hwave ? 0 : 2;
    const float bi0 = bias[ch], bi1 = bias[64 + ch], bi2 = bias[128 + ch], bi3 = bias[192 + ch];
    const float inv = gamma[ch] * rsqrtf(var[ch] + 1e-3f);
    const float shift = beta[ch] - mean[ch] * inv;
    float cprev[2][4];
    if (!FIRST) {
#pragma unroll
        for (int rr = 0; rr < 2; ++rr)
#pragma unroll
            for (int reg = 0; reg < 4; ++reg) {
                size_t pix = ((size_t)b * H_ + oy + rbase + rr) * W_ + (ox + kg * 4 + reg);
                cprev[rr][reg] = cbuf[pix * CO + ch];
            }
    } else {
#pragma unroll
        for (int rr = 0; rr < 2; ++rr)
#pragma unroll
            for (int reg = 0; reg < 4; ++reg) cprev[rr][reg] = 0.f;
    }

    __syncthreads();

    f32x4 acc[4][4];   // [gate][row-tile] -- constant indices only
#pragma unroll
    for (int g = 0; g < 4; ++g)
#pragma unroll
        for (int r = 0; r < 4; ++r) acc[g][r] = (f32x4){0.f, 0.f, 0.f, 0.f};

// ---- chunk maps: literal i only (every use constant-folds) ----
// x-wave: i<9: x-conv kpos=i (src sx);  i>=9: h-conv q1 kpos=i-9 (src sh1)
#define XW_WP(i)  ((i) < 9 ? (wkp + (size_t)(i) * 8192) : (wrp + (size_t)(((i) - 9) * 2 + 1) * 8192))
#define XW_SB(i)  ((i) < 9 ? sx : sh1)
#define XW_KQ(i)  ((i) < 9 ? (i) : (i) - 9)
// h-wave: i<9: h-conv q0 kpos=i (src sh0);  i>=9: q1 kpos=i-4 (src sh1)
#define HW_WP(i)  ((i) < 9 ? (wrp + (size_t)((i) * 2) * 8192) : (wrp + (size_t)(((i) - 4) * 2 + 1) * 8192))
#define HW_SB(i)  ((i) < 9 ? sh0 : sh1)
#define HW_KQ(i)  ((i) < 9 ? (i) : (i) - 4)

#define LOADW(dst, wp) { const unsigned short* wp_ = (wp);        \
    dst[0] = *(const bf16x8*)(wp_);                               \
    dst[1] = *(const bf16x8*)(wp_ + 2048);                        \
    dst[2] = *(const bf16x8*)(wp_ + 4096);                        \
    dst[3] = *(const bf16x8*)(wp_ + 6144); }

#define COMPUTE(i, SBM, KQM, BUF) {                               \
    const int kq_ = KQM(i);                                       \
    const int ky_ = kq_ / 3, kx_ = kq_ - ky_ * 3;                 \
    const unsigned short* sb_ = SBM(i);                           \
    bf16x8 a[4];                                                  \
    _Pragma("unroll")                                             \
    for (int r = 0; r < 4; ++r)                                   \
        a[r] = *(const bf16x8*)&sb_[((r + ky_) * 18 + ln + kx_) * PXS + kg * 8]; \
    __builtin_amdgcn_s_setprio(1);                                \
    _Pragma("unroll")                                             \
    for (int g = 0; g < 4; ++g)                                   \
        _Pragma("unroll")                                         \
        for (int r = 0; r < 4; ++r)                               \
            acc[g][r] = __builtin_amdgcn_mfma_f32_16x16x32_bf16(a[r], BUF[g], acc[g][r], 0, 0, 0); \
    __builtin_amdgcn_s_setprio(0); }

    if (!hwave) {
        constexpr int NCX = FIRST ? 9 : 14;
        bf16x8 P0[4], P1[4], P2[4], P3[4];
        LOADW(P0, XW_WP(0)); LOADW(P1, XW_WP(1)); LOADW(P2, XW_WP(2));
#define XSTEP(i, CUR, NXT)                                        \
        if ((i) < NCX) {                                          \
            if ((i) + 3 < NCX) LOADW(NXT, XW_WP((i) + 3));        \
            COMPUTE(i, XW_SB, XW_KQ, CUR);                        \
        }
        XSTEP(0,  P0, P3)  XSTEP(1,  P1, P0)  XSTEP(2,  P2, P1)  XSTEP(3,  P3, P2)
        XSTEP(4,  P0, P3)  XSTEP(5,  P1, P0)  XSTEP(6,  P2, P1)  XSTEP(7,  P3, P2)
        XSTEP(8,  P0, P3)  XSTEP(9,  P1, P0)  XSTEP(10, P2, P1)  XSTEP(11, P3, P2)
        XSTEP(12, P0, P3)  XSTEP(13, P1, P0)
#undef XSTEP
    } else if (!FIRST) {
        constexpr int NCH = 13;
        bf16x8 P0[4], P1[4], P2[4], P3[4];
        LOADW(P0, HW_WP(0)); LOADW(P1, HW_WP(1)); LOADW(P2, HW_WP(2));
#define HSTEP(i, CUR, NXT)                                        \
        if ((i) < NCH) {                                          \
            if ((i) + 3 < NCH) LOADW(NXT, HW_WP((i) + 3));        \
            COMPUTE(i, HW_SB, HW_KQ, CUR);                        \
        }
        HSTEP(0,  P0, P3)  HSTEP(1,  P1, P0)  HSTEP(2,  P2, P1)  HSTEP(3,  P3, P2)
        HSTEP(4,  P0, P3)  HSTEP(5,  P1, P0)  HSTEP(6,  P2, P1)  HSTEP(7,  P3, P2)
        HSTEP(8,  P0, P3)  HSTEP(9,  P1, P0)  HSTEP(10, P2, P1)  HSTEP(11, P3, P2)
        HSTEP(12, P0, P3)
#undef HSTEP
    }

    // ---- symmetric exchange: each role publishes the OTHER role's rows ----
    {
        const int pb = hwave ? 2 : 0;
#pragma unroll
        for (int g = 0; g < 4; ++g)
#pragma unroll
            for (int rr = 0; rr < 2; ++rr)
                *(f32x4*)&axx[((((sl * 4 + g) * 4 + (pb + rr)) * 16) + ln) * 20 + kg * 4] = acc[g][pb + rr];
    }
    __syncthreads();

    // ---- merge + epilogue for own rows (rbase..rbase+1), both roles ----
#pragma unroll
    for (int rr = 0; rr < 2; ++rr) {
        const int r = rbase + rr;
        const int gy = oy + r;
        f32x4 av[4];
#pragma unroll
        for (int g = 0; g < 4; ++g) {
            f32x4 v = *(const f32x4*)&axx[((((sl * 4 + g) * 4 + r) * 16) + ln) * 20 + kg * 4];
            av[g] = acc[g][r] + v;
        }
#pragma unroll
        for (int reg = 0; reg < 4; ++reg) {
            const int gx = ox + kg * 4 + reg;
            size_t pix = ((size_t)b * H_ + gy) * W_ + gx;
            float ig = hsig(av[0][reg] + bi0);
            float fg = hsig(av[1][reg] + bi1);
            float cg = ftanh(av[2][reg] + bi2);
            float og = hsig(av[3][reg] + bi3);
            float cv = fg * cprev[rr][reg] + ig * cg;
            float hv = og * ftanh(cv);
            cbuf[pix * CO + ch] = cv;                 // cached: re-read next step
            hout[pix * CO + ch] = f2bf(hv);
            __builtin_nontemporal_store(hv * inv + shift,
                &out[((((size_t)b * T_ + t) * H_ + gy) * W_ + gx) * CO + ch]);
        }
    }
}

extern "C" void kernel_launch(void* const* d_in, const int* in_sizes, int n_in,
                              void* d_out, int out_size, void* d_ws, size_t ws_size,
                              hipStream_t stream)
{
    (void)in_sizes; (void)n_in; (void)out_size; (void)ws_size;
    const float* x     = (const float*)d_in[0];
    const float* wk    = (const float*)d_in[1];
    const float* wr    = (const float*)d_in[2];
    const float* bias  = (const float*)d_in[3];
    const float* gamma = (const float*)d_in[4];
    const float* beta  = (const float*)d_in[5];
    const float* mean  = (const float*)d_in[6];
    const float* var   = (const float*)d_in[7];
    float* out = (float*)d_out;

    const size_t plane = (size_t)B_ * H_ * W_ * CO;           // 1,048,576 elems
    unsigned short* h0 = (unsigned short*)d_ws;               // bf16, 2 MB
    unsigned short* h1 = h0 + plane;                          // bf16, 2 MB
    float* cb = (float*)(h1 + plane);                         // fp32, 4 MB
    unsigned short* wkT = (unsigned short*)(cb + plane);      // 147 KB
    unsigned short* wrT = wkT + 9 * 256 * 32;                 // 295 KB

    transform_weights<<<576, 256, 0, stream>>>(wk, wr, wkT, wrT);

    for (int t = 0; t < T_; ++t) {
        const unsigned short* hin = (t & 1) ? h0 : h1;  // garbage at t==0 (unused)
        unsigned short* houtp     = (t & 1) ? h1 : h0;
        if (t == 0)
            convlstm_step<true><<<256, 512, 0, stream>>>(x, wkT, wrT, bias, gamma, beta, mean, var,
                                                         hin, houtp, cb, out, t);
        else
            convlstm_step<false><<<256, 512, 0, stream>>>(x, wkT, wrT, bias, gamma, beta, mean, var,
                                                          hin, houtp, cb, out, t);
    }
}

// Round 7
// 277.756 us; speedup vs baseline: 3.2770x; 2.4706x over previous
//
#include <hip/hip_runtime.h>
#include <math.h>

#define B_ 4
#define T_ 16
#define H_ 64
#define W_ 64
#define CIN 32
#define CO 64
#define NG 256   // 4*CO gate channels
#define PXS 40   // padded per-pixel stride in shorts (80 B): 16B-aligned, spreads LDS banks

typedef __attribute__((ext_vector_type(8))) short bf16x8;
typedef __attribute__((ext_vector_type(4))) float f32x4;

__device__ __forceinline__ float hsig(float z) {
    return fminf(1.f, fmaxf(0.f, 0.2f * z + 0.5f));
}

// fast tanh: v_exp_f32 + v_rcp_f32. Saturation exact at +/-inf.
__device__ __forceinline__ float ftanh(float x) {
    float e = __builtin_amdgcn_exp2f(x * 2.8853900817779268f);  // 2*log2(e)
    return 1.f - 2.f * __builtin_amdgcn_rcpf(e + 1.f);
}

__device__ __forceinline__ unsigned short f2bf(float f) {
    union { float f; unsigned u; } v; v.f = f;
    unsigned r = v.u + 0x7FFFu + ((v.u >> 16) & 1u);   // RTNE
    return (unsigned short)(r >> 16);
}

// Transpose+convert weights once per launch:
//   wkT[kpos][n=256][k=32]        from wk (3,3,32,256)
//   wrT[kpos][q=2][n=256][k=32]   from wr (3,3,64,256), q = cin chunk of 32
__global__ void transform_weights(const float* __restrict__ wk,
                                  const float* __restrict__ wr,
                                  unsigned short* __restrict__ wkT,
                                  unsigned short* __restrict__ wrT)
{
    int i = blockIdx.x * 256 + threadIdx.x;
    if (i < 9 * 256 * 32) {
        int k = i & 31, n = (i >> 5) & 255, kpos = i >> 13;
        wkT[i] = f2bf(wk[(kpos * 32 + k) * 256 + n]);
    }
    if (i < 9 * 2 * 256 * 32) {
        int k = i & 31, n = (i >> 5) & 255, q = (i >> 13) & 1, kpos = i >> 14;
        wrT[i] = f2bf(wr[(kpos * 64 + q * 32 + k) * 256 + n]);
    }
}

// One timestep. Block = 64 px (4 rows x 16 cols), 512 threads = 8 waves.
// Balanced k-split over the 27 (kpos,q) chunks of the fused conv:
//   x-waves (4-7): x-conv (9 chunks) + h-conv q1 kpos 0-4 (5)  = 14 chunks
//   h-waves (0-3): h-conv q0 (9 chunks) + q1 kpos 5-8 (4)      = 13 chunks
// Depth-4 weight-fragment pipeline, literal indices everywhere.
// CRITICAL (rule #20): acc[][] must NEVER be runtime-indexed — R4-R6 used
// acc[g][pb+rr] with runtime pb -> whole 64-reg accumulator demoted to
// scratch (VGPR=96, 151 MB/step scratch writes, MfmaUtil 6%). The
// exchange/merge/epilogue below is branch-specialized with LITERAL rows.
template<bool FIRST>
__global__ __launch_bounds__(512, 2)
void convlstm_step(const float* __restrict__ x,
                   const unsigned short* __restrict__ wkT,
                   const unsigned short* __restrict__ wrT,
                   const float* __restrict__ bias,
                   const float* __restrict__ gamma,
                   const float* __restrict__ beta,
                   const float* __restrict__ mean,
                   const float* __restrict__ var,
                   const unsigned short* __restrict__ hin,   // bf16 NHWC
                   unsigned short* __restrict__ hout,        // bf16 NHWC
                   float* __restrict__ cbuf,
                   float* __restrict__ out,
                   int t)
{
    __shared__ __align__(16) unsigned short sx[6 * 18 * PXS];        //  8.6 KB
    __shared__ __align__(16) unsigned short shm[2][6 * 18 * PXS];    // 17.3 KB
    // partial exchange: [slice4][gate4][row4][ch16][px 16 + 4 pad] fp32 = 80 KB
    __shared__ __align__(16) float axx[4 * 4 * 4 * 16 * 20];

    const int tid = threadIdx.x;
    const int wv = tid >> 6, lane = tid & 63;
    const int ln = lane & 15, kg = lane >> 4;
    const bool hwave = (wv < 4);
    const int sl = wv & 3;                 // n-slice: ch = sl*16 + ln

    const int bi = blockIdx.x;
    const int b = bi >> 6, tile = bi & 63;
    const int oy = (tile >> 2) * 4;        // 16 row-tiles
    const int ox = (tile & 3) * 16;        // 4 col-tiles

    unsigned short* sh0 = shm[0];
    unsigned short* sh1 = shm[1];

    // ---- parallel staging: x-waves stage sx, h-waves stage sh ----
    if (!hwave) {
        // x halo (fp32 -> bf16): 108 positions x 4 chunks of 8 cin = 432 elems
#pragma unroll
        for (int i = 0; i < 2; ++i) {
            int e = (tid - 256) + i * 256;
            if (e < 432) {
                int c8 = e & 3, p = e >> 2;
                int row = p / 18, col = p - row * 18;
                int gy = oy - 1 + row, gx = ox - 1 + col;
                float4 v0 = make_float4(0.f, 0.f, 0.f, 0.f), v1 = v0;
                if ((unsigned)gy < (unsigned)H_ && (unsigned)gx < (unsigned)W_) {
                    const float* p32 = &x[((((size_t)b * T_ + t) * H_ + gy) * W_ + gx) * CIN + c8 * 8];
                    v0 = *(const float4*)p32; v1 = *(const float4*)(p32 + 4);
                }
                unsigned short* d = &sx[(row * 18 + col) * PXS + c8 * 8];
                d[0] = f2bf(v0.x); d[1] = f2bf(v0.y); d[2] = f2bf(v0.z); d[3] = f2bf(v0.w);
                d[4] = f2bf(v1.x); d[5] = f2bf(v1.y); d[6] = f2bf(v1.z); d[7] = f2bf(v1.w);
            }
        }
    } else if (!FIRST) {
        // h halo (bf16 copy): 108 positions x 8 octs of 8 ch = 864 elems
#pragma unroll
        for (int i = 0; i < 4; ++i) {
            int e = tid + i * 256;
            if (e < 864) {
                int o = e & 7, p = e >> 3;
                int row = p / 18, col = p - row * 18;
                int gy = oy - 1 + row, gx = ox - 1 + col;
                uint4 v = make_uint4(0u, 0u, 0u, 0u);
                if ((unsigned)gy < (unsigned)H_ && (unsigned)gx < (unsigned)W_)
                    v = *(const uint4*)&hin[(((size_t)b * H_ + gy) * W_ + gx) * CO + o * 8];
                int q = o >> 2, s4 = o & 3;
                *(uint4*)&shm[q][(row * 18 + col) * PXS + s4 * 8] = v;
            }
        }
    }

    const int nbase = sl * 16 + ln;
    const int ch = nbase;
    const unsigned short* wkp = wkT + (size_t)nbase * 32 + kg * 8;
    const unsigned short* wrp = wrT + (size_t)nbase * 32 + kg * 8;

    // ---- hoisted epilogue inputs (both roles, their own row-pair) ----
    // h-waves own rows 0-1, x-waves own rows 2-3 (address math only — values).
    const int rbase = hwave ? 0 : 2;
    const float bi0 = bias[ch], bi1 = bias[64 + ch], bi2 = bias[128 + ch], bi3 = bias[192 + ch];
    const float inv = gamma[ch] * rsqrtf(var[ch] + 1e-3f);
    const float shift = beta[ch] - mean[ch] * inv;
    float cprev[2][4];
    if (!FIRST) {
#pragma unroll
        for (int rr = 0; rr < 2; ++rr)
#pragma unroll
            for (int reg = 0; reg < 4; ++reg) {
                size_t pix = ((size_t)b * H_ + oy + rbase + rr) * W_ + (ox + kg * 4 + reg);
                cprev[rr][reg] = cbuf[pix * CO + ch];
            }
    } else {
#pragma unroll
        for (int rr = 0; rr < 2; ++rr)
#pragma unroll
            for (int reg = 0; reg < 4; ++reg) cprev[rr][reg] = 0.f;
    }

    __syncthreads();

    f32x4 acc[4][4];   // [gate][row-tile] -- LITERAL indices only, everywhere
#pragma unroll
    for (int g = 0; g < 4; ++g)
#pragma unroll
        for (int r = 0; r < 4; ++r) acc[g][r] = (f32x4){0.f, 0.f, 0.f, 0.f};

// ---- chunk maps: literal i only (every use constant-folds) ----
// x-wave: i<9: x-conv kpos=i (src sx);  i>=9: h-conv q1 kpos=i-9 (src sh1)
#define XW_WP(i)  ((i) < 9 ? (wkp + (size_t)(i) * 8192) : (wrp + (size_t)(((i) - 9) * 2 + 1) * 8192))
#define XW_SB(i)  ((i) < 9 ? sx : sh1)
#define XW_KQ(i)  ((i) < 9 ? (i) : (i) - 9)
// h-wave: i<9: h-conv q0 kpos=i (src sh0);  i>=9: q1 kpos=i-4 (src sh1)
#define HW_WP(i)  ((i) < 9 ? (wrp + (size_t)((i) * 2) * 8192) : (wrp + (size_t)(((i) - 4) * 2 + 1) * 8192))
#define HW_SB(i)  ((i) < 9 ? sh0 : sh1)
#define HW_KQ(i)  ((i) < 9 ? (i) : (i) - 4)

#define LOADW(dst, wp) { const unsigned short* wp_ = (wp);        \
    dst[0] = *(const bf16x8*)(wp_);                               \
    dst[1] = *(const bf16x8*)(wp_ + 2048);                        \
    dst[2] = *(const bf16x8*)(wp_ + 4096);                        \
    dst[3] = *(const bf16x8*)(wp_ + 6144); }

#define COMPUTE(i, SBM, KQM, BUF) {                               \
    const int kq_ = KQM(i);                                       \
    const int ky_ = kq_ / 3, kx_ = kq_ - ky_ * 3;                 \
    const unsigned short* sb_ = SBM(i);                           \
    bf16x8 a[4];                                                  \
    _Pragma("unroll")                                             \
    for (int r = 0; r < 4; ++r)                                   \
        a[r] = *(const bf16x8*)&sb_[((r + ky_) * 18 + ln + kx_) * PXS + kg * 8]; \
    __builtin_amdgcn_s_setprio(1);                                \
    _Pragma("unroll")                                             \
    for (int g = 0; g < 4; ++g)                                   \
        _Pragma("unroll")                                         \
        for (int r = 0; r < 4; ++r)                               \
            acc[g][r] = __builtin_amdgcn_mfma_f32_16x16x32_bf16(a[r], BUF[g], acc[g][r], 0, 0, 0); \
    __builtin_amdgcn_s_setprio(0); }

    if (!hwave) {
        constexpr int NCX = FIRST ? 9 : 14;
        bf16x8 P0[4], P1[4], P2[4], P3[4];
        LOADW(P0, XW_WP(0)); LOADW(P1, XW_WP(1)); LOADW(P2, XW_WP(2));
#define XSTEP(i, CUR, NXT)                                        \
        if ((i) < NCX) {                                          \
            if ((i) + 3 < NCX) LOADW(NXT, XW_WP((i) + 3));        \
            COMPUTE(i, XW_SB, XW_KQ, CUR);                        \
        }
        XSTEP(0,  P0, P3)  XSTEP(1,  P1, P0)  XSTEP(2,  P2, P1)  XSTEP(3,  P3, P2)
        XSTEP(4,  P0, P3)  XSTEP(5,  P1, P0)  XSTEP(6,  P2, P1)  XSTEP(7,  P3, P2)
        XSTEP(8,  P0, P3)  XSTEP(9,  P1, P0)  XSTEP(10, P2, P1)  XSTEP(11, P3, P2)
        XSTEP(12, P0, P3)  XSTEP(13, P1, P0)
#undef XSTEP
    } else if (!FIRST) {
        constexpr int NCH = 13;
        bf16x8 P0[4], P1[4], P2[4], P3[4];
        LOADW(P0, HW_WP(0)); LOADW(P1, HW_WP(1)); LOADW(P2, HW_WP(2));
#define HSTEP(i, CUR, NXT)                                        \
        if ((i) < NCH) {                                          \
            if ((i) + 3 < NCH) LOADW(NXT, HW_WP((i) + 3));        \
            COMPUTE(i, HW_SB, HW_KQ, CUR);                        \
        }
        HSTEP(0,  P0, P3)  HSTEP(1,  P1, P0)  HSTEP(2,  P2, P1)  HSTEP(3,  P3, P2)
        HSTEP(4,  P0, P3)  HSTEP(5,  P1, P0)  HSTEP(6,  P2, P1)  HSTEP(7,  P3, P2)
        HSTEP(8,  P0, P3)  HSTEP(9,  P1, P0)  HSTEP(10, P2, P1)  HSTEP(11, P3, P2)
        HSTEP(12, P0, P3)
#undef HSTEP
    }

    // ---- symmetric exchange: LITERAL row indices in each uniform branch ----
    // x-waves publish rows 0,1 (h-waves' epilogue half); h-waves publish 2,3.
    if (!hwave) {
#pragma unroll
        for (int g = 0; g < 4; ++g) {
            *(f32x4*)&axx[((((sl * 4 + g) * 4 + 0) * 16) + ln) * 20 + kg * 4] = acc[g][0];
            *(f32x4*)&axx[((((sl * 4 + g) * 4 + 1) * 16) + ln) * 20 + kg * 4] = acc[g][1];
        }
    } else {
#pragma unroll
        for (int g = 0; g < 4; ++g) {
            *(f32x4*)&axx[((((sl * 4 + g) * 4 + 2) * 16) + ln) * 20 + kg * 4] = acc[g][2];
            *(f32x4*)&axx[((((sl * 4 + g) * 4 + 3) * 16) + ln) * 20 + kg * 4] = acc[g][3];
        }
    }
    __syncthreads();

    // ---- merge + epilogue, literal rows per branch ----
#define EPILOG(R, RR) {                                                          \
        const int gy = oy + (R);                                                 \
        f32x4 av[4];                                                             \
        _Pragma("unroll")                                                        \
        for (int g = 0; g < 4; ++g) {                                            \
            f32x4 v = *(const f32x4*)&axx[((((sl * 4 + g) * 4 + (R)) * 16) + ln) * 20 + kg * 4]; \
            av[g] = acc[g][R] + v;                                               \
        }                                                                        \
        _Pragma("unroll")                                                        \
        for (int reg = 0; reg < 4; ++reg) {                                      \
            const int gx = ox + kg * 4 + reg;                                    \
            size_t pix = ((size_t)b * H_ + gy) * W_ + gx;                        \
            float ig = hsig(av[0][reg] + bi0);                                   \
            float fg = hsig(av[1][reg] + bi1);                                   \
            float cg = ftanh(av[2][reg] + bi2);                                  \
            float og = hsig(av[3][reg] + bi3);                                   \
            float cv = fg * cprev[RR][reg] + ig * cg;                            \
            float hv = og * ftanh(cv);                                           \
            cbuf[pix * CO + ch] = cv;                                            \
            hout[pix * CO + ch] = f2bf(hv);                                      \
            __builtin_nontemporal_store(hv * inv + shift,                        \
                &out[((((size_t)b * T_ + t) * H_ + gy) * W_ + gx) * CO + ch]);   \
        }                                                                        \
    }

    if (hwave) { EPILOG(0, 0) EPILOG(1, 1) }
    else       { EPILOG(2, 0) EPILOG(3, 1) }
#undef EPILOG
}

extern "C" void kernel_launch(void* const* d_in, const int* in_sizes, int n_in,
                              void* d_out, int out_size, void* d_ws, size_t ws_size,
                              hipStream_t stream)
{
    (void)in_sizes; (void)n_in; (void)out_size; (void)ws_size;
    const float* x     = (const float*)d_in[0];
    const float* wk    = (const float*)d_in[1];
    const float* wr    = (const float*)d_in[2];
    const float* bias  = (const float*)d_in[3];
    const float* gamma = (const float*)d_in[4];
    const float* beta  = (const float*)d_in[5];
    const float* mean  = (const float*)d_in[6];
    const float* var   = (const float*)d_in[7];
    float* out = (float*)d_out;

    const size_t plane = (size_t)B_ * H_ * W_ * CO;           // 1,048,576 elems
    unsigned short* h0 = (unsigned short*)d_ws;               // bf16, 2 MB
    unsigned short* h1 = h0 + plane;                          // bf16, 2 MB
    float* cb = (float*)(h1 + plane);                         // fp32, 4 MB
    unsigned short* wkT = (unsigned short*)(cb + plane);      // 147 KB
    unsigned short* wrT = wkT + 9 * 256 * 32;                 // 295 KB

    transform_weights<<<576, 256, 0, stream>>>(wk, wr, wkT, wrT);

    for (int t = 0; t < T_; ++t) {
        const unsigned short* hin = (t & 1) ? h0 : h1;  // garbage at t==0 (unused)
        unsigned short* houtp     = (t & 1) ? h1 : h0;
        if (t == 0)
            convlstm_step<true><<<256, 512, 0, stream>>>(x, wkT, wrT, bias, gamma, beta, mean, var,
                                                         hin, houtp, cb, out, t);
        else
            convlstm_step<false><<<256, 512, 0, stream>>>(x, wkT, wrT, bias, gamma, beta, mean, var,
                                                          hin, houtp, cb, out, t);
    }
}